// Round 3
// baseline (655.525 us; speedup 1.0000x reference)
//
#include <hip/hip_runtime.h>

// FCtL attention fusion for MI355X (gfx950).
// B=1, C=256 (inplanes), P=64 (planes), H=W=96 -> N=M=9216.
//
// Pipeline:
//   k1: per-channel means of x,y + fp32->bf16 conversion (xb, yb)
//   k2: weight fp32->bf16 conversion + qmean/kmean = W @ mean (fp32)
//   k3: MFMA projections: Q[n][p], K[m][p] (centered), V[c][m]   (bf16)
//   k4: flash attention, Q-tile=64 rows, KV-tile=64, M-split=2, grid 288,
//       4 waves/block, online softmax in registers, unnormalized partials
//   k5: combine 2 splits + transpose to [C][N] + gamma scale
//
// MFMA 16x16x32 bf16 layouts (learn_hip verified):
//   A: row = lane&15,                 k = (lane>>4)*8 + i   (8 contig bf16)
//   B: col = lane&15,                 k = (lane>>4)*8 + i
//   C/D: col = lane&15,               row = (lane>>4)*4 + reg

typedef __attribute__((ext_vector_type(8))) short short8;
typedef __attribute__((ext_vector_type(8))) unsigned short ushort8;
typedef __attribute__((ext_vector_type(4))) float f32x4;

#define C_DIM 256
#define P_DIM 64
#define N_DIM 9216
#define NT    144     // n-tiles of 64
#define HALF_M 4608
#define KV_TILES 72   // per split

__device__ __forceinline__ unsigned short f2b(float f) {
  unsigned int u = __float_as_uint(f);
  u += 0x7fffu + ((u >> 16) & 1u);   // RNE (finite values only)
  return (unsigned short)(u >> 16);
}

__device__ __forceinline__ f32x4 mfma16(short8 a, short8 b, f32x4 c) {
  return __builtin_amdgcn_mfma_f32_16x16x32_bf16(a, b, c, 0, 0, 0);
}

// ---------------- k1: means + bf16 conversion ----------------
__global__ void k1_mean_conv(const float* __restrict__ x, const float* __restrict__ y,
                             unsigned short* __restrict__ xb, unsigned short* __restrict__ yb,
                             float* __restrict__ xmean, float* __restrict__ ymean) {
  int b = blockIdx.x;
  const float* src = (b < C_DIM) ? x : y;
  unsigned short* dst = (b < C_DIM) ? xb : yb;
  float* mout = (b < C_DIM) ? xmean : ymean;
  int c = b & (C_DIM - 1);
  const float4* row = (const float4*)(src + (size_t)c * N_DIM);
  ushort4* orow = (ushort4*)(dst + (size_t)c * N_DIM);
  int tid = threadIdx.x;
  float s = 0.f;
  for (int i = tid; i < N_DIM / 4; i += 256) {
    float4 v = row[i];
    s += v.x + v.y + v.z + v.w;
    ushort4 o;
    o.x = f2b(v.x); o.y = f2b(v.y); o.z = f2b(v.z); o.w = f2b(v.w);
    orow[i] = o;
  }
#pragma unroll
  for (int off = 1; off < 64; off <<= 1) s += __shfl_xor(s, off);
  __shared__ float red[4];
  if ((tid & 63) == 0) red[tid >> 6] = s;
  __syncthreads();
  if (tid == 0) mout[c] = (red[0] + red[1] + red[2] + red[3]) * (1.f / (float)N_DIM);
}

// ---------------- k2: weight conversion + projected means ----------------
__global__ void k2_wconv(const float* __restrict__ Wv, const float* __restrict__ Wq,
                         const float* __restrict__ Wk,
                         const float* __restrict__ xmean, const float* __restrict__ ymean,
                         unsigned short* __restrict__ Wvb, unsigned short* __restrict__ Wqb,
                         unsigned short* __restrict__ Wkb,
                         float* __restrict__ qmean, float* __restrict__ kmean) {
  int b = blockIdx.x, t = threadIdx.x;
  if (b < 256) {
    int i = b * 256 + t; Wvb[i] = f2b(Wv[i]);
  } else if (b < 320) {
    int i = (b - 256) * 256 + t; Wqb[i] = f2b(Wq[i]);
  } else if (b < 384) {
    int i = (b - 320) * 256 + t; Wkb[i] = f2b(Wk[i]);
  } else if (t < 128) {
    // qmean[p] = Wq[p,:] . xmean   (bias cancels in centering)
    int p = t & 63;
    const float* W = (t < 64) ? Wq : Wk;
    const float* mv = (t < 64) ? xmean : ymean;
    float s = 0.f;
    for (int cc = 0; cc < 256; cc++) s += W[p * 256 + cc] * mv[cc];
    ((t < 64) ? qmean : kmean)[p] = s;
  }
}

// ---------------- k3: MFMA projections ----------------
// blocks 0..143: V-tile (V[c][m]); 144..287: Q-tile (Q[n][p]); 288..431: K-tile
__global__ void k3_proj(const unsigned short* __restrict__ xb, const unsigned short* __restrict__ yb,
                        const unsigned short* __restrict__ Wvb, const unsigned short* __restrict__ Wqb,
                        const unsigned short* __restrict__ Wkb,
                        const float* __restrict__ qmean, const float* __restrict__ kmean,
                        unsigned short* __restrict__ Qb, unsigned short* __restrict__ Kb,
                        unsigned short* __restrict__ Vb) {
  __shared__ unsigned short T[64][264];  // transposed input tile [m/n][c], 16B-aligned rows, ~2-way banks
  int b = blockIdx.x;
  int role = b / NT;       // 0=V 1=Q 2=K
  int tile = b % NT;
  int m0 = tile * 64;
  int tid = threadIdx.x;
  int w = tid >> 6, lane = tid & 63, l16 = lane & 15, g4 = lane >> 4;

  const unsigned short* src = (role == 1) ? xb : yb;
  {
    int c = tid;  // 256 threads = 256 channels
    const unsigned short* sr = src + (size_t)c * N_DIM + m0;
#pragma unroll
    for (int j = 0; j < 8; j++) {
      ushort8 v = *(const ushort8*)&sr[j * 8];
#pragma unroll
      for (int i = 0; i < 8; i++) T[j * 8 + i][c] = v[i];
    }
  }
  __syncthreads();

  if (role == 0) {
    // rows = c_out (wave owns 64), cols = m (64), k = c_in (256)
    f32x4 acc[4][4];
#pragma unroll
    for (int rf = 0; rf < 4; rf++)
#pragma unroll
      for (int cf = 0; cf < 4; cf++) acc[rf][cf] = (f32x4)0.f;
#pragma unroll
    for (int kk = 0; kk < 8; kk++) {
      short8 bf[4];
#pragma unroll
      for (int cf = 0; cf < 4; cf++)
        bf[cf] = *(const short8*)&T[cf * 16 + l16][kk * 32 + g4 * 8];
#pragma unroll
      for (int rf = 0; rf < 4; rf++) {
        short8 af = *(const short8*)&Wvb[(size_t)(w * 64 + rf * 16 + l16) * 256 + kk * 32 + g4 * 8];
#pragma unroll
        for (int cf = 0; cf < 4; cf++) acc[rf][cf] = mfma16(af, bf[cf], acc[rf][cf]);
      }
    }
#pragma unroll
    for (int rf = 0; rf < 4; rf++)
#pragma unroll
      for (int cf = 0; cf < 4; cf++)
#pragma unroll
        for (int r = 0; r < 4; r++) {
          int co = w * 64 + rf * 16 + g4 * 4 + r;
          int m = m0 + cf * 16 + l16;
          Vb[(size_t)co * N_DIM + m] = f2b(acc[rf][cf][r]);
        }
  } else {
    const unsigned short* Wb = (role == 1) ? Wqb : Wkb;
    const float* mean = (role == 1) ? qmean : kmean;
    unsigned short* Ob = (role == 1) ? Qb : Kb;
    // rows = n (wave owns 16), cols = p (64), k = c (256)
    f32x4 acc[4];
#pragma unroll
    for (int cf = 0; cf < 4; cf++) acc[cf] = (f32x4)0.f;
#pragma unroll
    for (int kk = 0; kk < 8; kk++) {
      short8 af = *(const short8*)&T[w * 16 + l16][kk * 32 + g4 * 8];
#pragma unroll
      for (int cf = 0; cf < 4; cf++) {
        short8 bf = *(const short8*)&Wb[(size_t)(cf * 16 + l16) * 256 + kk * 32 + g4 * 8];
        acc[cf] = mfma16(af, bf, acc[cf]);
      }
    }
#pragma unroll
    for (int cf = 0; cf < 4; cf++)
#pragma unroll
      for (int r = 0; r < 4; r++) {
        int n = m0 + w * 16 + g4 * 4 + r;
        int p = cf * 16 + l16;
        Ob[(size_t)n * 64 + p] = f2b(acc[cf][r] - mean[p]);
      }
  }
}

// ---------------- k4: flash attention ----------------
// grid 288: b&1 = M-split half, b>>1 = n-tile. 256 threads (4 waves).
// Wave w: QK strip m=[w*16,w*16+16); PV c-chunk [w*64,(w+1)*64).
__global__ __launch_bounds__(256, 2)
void k4_attn(const unsigned short* __restrict__ Qb, const unsigned short* __restrict__ Kb,
             const unsigned short* __restrict__ Vb,
             float* __restrict__ po, float* __restrict__ m_arr, float* __restrict__ l_arr) {
  __shared__ unsigned short Kt[64][72];
  __shared__ unsigned short Vt[256][72];
  __shared__ unsigned short Pt[64][72];   // also Q staging
  __shared__ float mrow[64], lrow[64], frow[64], pm[4][64], ps[4][64];

  int b = blockIdx.x;
  int s = b & 1;
  int n0 = (b >> 1) * 64;
  int tid = threadIdx.x;
  int w = tid >> 6, lane = tid & 63, l16 = lane & 15, g4 = lane >> 4;

  // stage Q tile -> Pt -> registers (held for whole sweep)
  for (int idx = tid; idx < 64 * 8; idx += 256) {
    int r = idx >> 3, j = idx & 7;
    *(ushort8*)&Pt[r][j * 8] = *(const ushort8*)&Qb[(size_t)(n0 + r) * 64 + j * 8];
  }
  if (tid < 64) { mrow[tid] = -3e38f; lrow[tid] = 0.f; }
  __syncthreads();
  short8 qf[4][2];
#pragma unroll
  for (int nf = 0; nf < 4; nf++)
#pragma unroll
    for (int kk = 0; kk < 2; kk++)
      qf[nf][kk] = *(const short8*)&Pt[nf * 16 + l16][kk * 32 + g4 * 8];
  f32x4 acc[4][4];
#pragma unroll
  for (int rf = 0; rf < 4; rf++)
#pragma unroll
    for (int cf = 0; cf < 4; cf++) acc[rf][cf] = (f32x4)0.f;
  __syncthreads();  // qf loaded before Pt reuse

  int mbase = s * HALF_M;
  for (int t = 0; t < KV_TILES; t++) {
    int m0 = mbase + t * 64;
    // A: stage K (8KB) + V (32KB)
    for (int idx = tid; idx < 64 * 8; idx += 256) {
      int r = idx >> 3, j = idx & 7;
      *(ushort8*)&Kt[r][j * 8] = *(const ushort8*)&Kb[(size_t)(m0 + r) * 64 + j * 8];
    }
    for (int idx = tid; idx < 256 * 8; idx += 256) {
      int r = idx >> 3, j = idx & 7;
      *(ushort8*)&Vt[r][j * 8] = *(const ushort8*)&Vb[(size_t)r * N_DIM + m0 + j * 8];
    }
    __syncthreads();

    // B: QK^T strip -> registers; per-wave partial row max
    f32x4 sa[4];
#pragma unroll
    for (int nf = 0; nf < 4; nf++) sa[nf] = (f32x4)0.f;
#pragma unroll
    for (int kk = 0; kk < 2; kk++) {
      short8 kf = *(const short8*)&Kt[w * 16 + l16][kk * 32 + g4 * 8];
#pragma unroll
      for (int nf = 0; nf < 4; nf++) sa[nf] = mfma16(qf[nf][kk], kf, sa[nf]);
    }
#pragma unroll
    for (int nf = 0; nf < 4; nf++)
#pragma unroll
      for (int r = 0; r < 4; r++) {
        float v = sa[nf][r];
#pragma unroll
        for (int off = 1; off < 16; off <<= 1) v = fmaxf(v, __shfl_xor(v, off));
        if (l16 == 0) pm[w][nf * 16 + g4 * 4 + r] = v;
      }
    __syncthreads();

    // C: merge row max, rescale factor
    if (tid < 64) {
      float mold = mrow[tid];
      float mx = fmaxf(fmaxf(pm[0][tid], pm[1][tid]), fmaxf(pm[2][tid], pm[3][tid]));
      float mnew = fmaxf(mold, mx);
      frow[tid] = __expf(mold - mnew);
      mrow[tid] = mnew;
    }
    __syncthreads();

    // D: P = exp(S - m), partial sums, Pt bf16, acc rescale
#pragma unroll
    for (int nf = 0; nf < 4; nf++) {
#pragma unroll
      for (int r = 0; r < 4; r++) {
        int row = nf * 16 + g4 * 4 + r;
        float p = __expf(sa[nf][r] - mrow[row]);
        Pt[row][w * 16 + l16] = f2b(p);
        float sv = p;
#pragma unroll
        for (int off = 1; off < 16; off <<= 1) sv += __shfl_xor(sv, off);
        if (l16 == 0) ps[w][row] = sv;
        float f = frow[row];
#pragma unroll
        for (int cf = 0; cf < 4; cf++) acc[nf][cf][r] *= f;
      }
    }
    __syncthreads();

    // E (tid<64, overlaps F): l update
    if (tid < 64)
      lrow[tid] = lrow[tid] * frow[tid] + ps[0][tid] + ps[1][tid] + ps[2][tid] + ps[3][tid];

    // F: PV accumulate
#pragma unroll
    for (int kk = 0; kk < 2; kk++) {
      short8 vf[4];
#pragma unroll
      for (int cf = 0; cf < 4; cf++)
        vf[cf] = *(const short8*)&Vt[w * 64 + cf * 16 + l16][kk * 32 + g4 * 8];
#pragma unroll
      for (int rf = 0; rf < 4; rf++) {
        short8 pf = *(const short8*)&Pt[rf * 16 + l16][kk * 32 + g4 * 8];
#pragma unroll
        for (int cf = 0; cf < 4; cf++) acc[rf][cf] = mfma16(pf, vf[cf], acc[rf][cf]);
      }
    }
    __syncthreads();  // protect Kt/Vt/Pt for next iter
  }

  // epilogue: unnormalized partials + stats
  float* poS = po + (size_t)s * N_DIM * C_DIM;
#pragma unroll
  for (int rf = 0; rf < 4; rf++)
#pragma unroll
    for (int cf = 0; cf < 4; cf++)
#pragma unroll
      for (int r = 0; r < 4; r++) {
        int n = n0 + rf * 16 + g4 * 4 + r;
        int c = w * 64 + cf * 16 + l16;
        poS[(size_t)n * C_DIM + c] = acc[rf][cf][r];
      }
  if (tid < 64) {
    m_arr[s * N_DIM + n0 + tid] = mrow[tid];
    l_arr[s * N_DIM + n0 + tid] = lrow[tid];
  }
}

// ---------------- k5: combine splits, transpose to [C][N], gamma ----------------
__global__ void k5_combine(const float* __restrict__ po, const float* __restrict__ m_arr,
                           const float* __restrict__ l_arr, const float* __restrict__ gamma,
                           float* __restrict__ out) {
  __shared__ float TT[64][65];
  int b = blockIdx.x;
  int c0 = (b & 3) * 64;
  int n0 = (b >> 2) * 64;
  float g = gamma[0];
  int tid = threadIdx.x;
#pragma unroll
  for (int r = 0; r < 16; r++) {
    int idx = r * 256 + tid;
    int nl = idx >> 6, cl = idx & 63;
    int n = n0 + nl;
    float m0v = m_arr[n], m1v = m_arr[N_DIM + n];
    float M = fmaxf(m0v, m1v);
    float w0 = __expf(m0v - M), w1 = __expf(m1v - M);
    float denom = l_arr[n] * w0 + l_arr[N_DIM + n] * w1;
    float v0 = po[(size_t)n * C_DIM + c0 + cl];
    float v1 = po[((size_t)N_DIM + n) * C_DIM + c0 + cl];
    TT[cl][nl] = (v0 * w0 + v1 * w1) / denom;
  }
  __syncthreads();
#pragma unroll
  for (int r = 0; r < 16; r++) {
    int idx = r * 256 + tid;
    int cl = idx >> 6, nl = idx & 63;
    out[(size_t)(c0 + cl) * N_DIM + n0 + nl] = g * TT[cl][nl];
  }
}

// ---------------- launch ----------------
extern "C" void kernel_launch(void* const* d_in, const int* in_sizes, int n_in,
                              void* d_out, int out_size, void* d_ws, size_t ws_size,
                              hipStream_t stream) {
  const float* x  = (const float*)d_in[0];
  const float* y  = (const float*)d_in[1];
  const float* Wv = (const float*)d_in[2];
  const float* Wq = (const float*)d_in[3];
  const float* Wk = (const float*)d_in[5];
  const float* gamma = (const float*)d_in[7];
  float* out = (float*)d_out;

  char* ws = (char*)d_ws;
  constexpr size_t OFF_XMEAN = 0;
  constexpr size_t OFF_YMEAN = 1024;
  constexpr size_t OFF_QMEAN = 2048;
  constexpr size_t OFF_KMEAN = 2560;
  constexpr size_t OFF_XB    = 4096;
  constexpr size_t OFF_YB    = OFF_XB + 4718592;
  constexpr size_t OFF_WVB   = OFF_YB + 4718592;
  constexpr size_t OFF_WQB   = OFF_WVB + 131072;
  constexpr size_t OFF_WKB   = OFF_WQB + 32768;
  constexpr size_t OFF_QB    = OFF_WKB + 32768;
  constexpr size_t OFF_KB    = OFF_QB + 1179648;
  constexpr size_t OFF_VB    = OFF_KB + 1179648;
  constexpr size_t OFF_PO    = OFF_VB + 4718592;
  constexpr size_t OFF_M     = OFF_PO + 18874368;
  constexpr size_t OFF_L     = OFF_M + 73728;   // total ~35.7 MB

  float* xmean = (float*)(ws + OFF_XMEAN);
  float* ymean = (float*)(ws + OFF_YMEAN);
  float* qmean = (float*)(ws + OFF_QMEAN);
  float* kmean = (float*)(ws + OFF_KMEAN);
  unsigned short* xb  = (unsigned short*)(ws + OFF_XB);
  unsigned short* yb  = (unsigned short*)(ws + OFF_YB);
  unsigned short* Wvb = (unsigned short*)(ws + OFF_WVB);
  unsigned short* Wqb = (unsigned short*)(ws + OFF_WQB);
  unsigned short* Wkb = (unsigned short*)(ws + OFF_WKB);
  unsigned short* Qb  = (unsigned short*)(ws + OFF_QB);
  unsigned short* Kb  = (unsigned short*)(ws + OFF_KB);
  unsigned short* Vb  = (unsigned short*)(ws + OFF_VB);
  float* po    = (float*)(ws + OFF_PO);
  float* m_arr = (float*)(ws + OFF_M);
  float* l_arr = (float*)(ws + OFF_L);

  k1_mean_conv<<<512, 256, 0, stream>>>(x, y, xb, yb, xmean, ymean);
  k2_wconv<<<385, 256, 0, stream>>>(Wv, Wq, Wk, xmean, ymean, Wvb, Wqb, Wkb, qmean, kmean);
  k3_proj<<<432, 256, 0, stream>>>(xb, yb, Wvb, Wqb, Wkb, qmean, kmean, Qb, Kb, Vb);
  k4_attn<<<288, 256, 0, stream>>>(Qb, Kb, Vb, po, m_arr, l_arr);
  k5_combine<<<576, 256, 0, stream>>>(po, m_arr, l_arr, gamma, out);
}

// Round 7
// 356.336 us; speedup vs baseline: 1.8396x; 1.8396x over previous
//
#include <hip/hip_runtime.h>

// FCtL attention fusion for MI355X (gfx950).
// B=1, C=256 (inplanes), P=64 (planes), H=W=96 -> N=M=9216.
//
// Round 3 restructure (from rocprof: MfmaUtil 3.9%, Occupancy 13.4%,
// 5 barriers/iter -> latency-bound):
//   - k4: each wave owns 16 Q-rows x full m-extent -> softmax is wave-local
//     (register + 16-lane shfl), 2 barriers/iter, no cross-wave LDS merges.
//   - M-splits 2 -> 4 (grid 576, ~2.25 blocks/CU), po stored bf16.
//
// MFMA 16x16x32 bf16 layouts (learn_hip verified):
//   A: row = lane&15,  k = (lane>>4)*8 + i   (8 contig bf16)
//   B: col = lane&15,  k = (lane>>4)*8 + i
//   C/D: col = lane&15, row = (lane>>4)*4 + reg

typedef __attribute__((ext_vector_type(8))) short short8;
typedef __attribute__((ext_vector_type(8))) unsigned short ushort8;
typedef __attribute__((ext_vector_type(4))) float f32x4;

#define C_DIM 256
#define P_DIM 64
#define N_DIM 9216
#define NT    144     // n-tiles of 64
#define SPLITS 4
#define MQ    (N_DIM / SPLITS)   // 2304
#define KV_TILES (MQ / 64)       // 36

__device__ __forceinline__ unsigned short f2b(float f) {
  unsigned int u = __float_as_uint(f);
  u += 0x7fffu + ((u >> 16) & 1u);   // RNE (finite values only)
  return (unsigned short)(u >> 16);
}

__device__ __forceinline__ float b2f(unsigned short h) {
  return __uint_as_float(((unsigned int)h) << 16);
}

__device__ __forceinline__ f32x4 mfma16(short8 a, short8 b, f32x4 c) {
  return __builtin_amdgcn_mfma_f32_16x16x32_bf16(a, b, c, 0, 0, 0);
}

// ---------------- k1: means + bf16 conversion ----------------
__global__ void k1_mean_conv(const float* __restrict__ x, const float* __restrict__ y,
                             unsigned short* __restrict__ xb, unsigned short* __restrict__ yb,
                             float* __restrict__ xmean, float* __restrict__ ymean) {
  int b = blockIdx.x;
  const float* src = (b < C_DIM) ? x : y;
  unsigned short* dst = (b < C_DIM) ? xb : yb;
  float* mout = (b < C_DIM) ? xmean : ymean;
  int c = b & (C_DIM - 1);
  const float4* row = (const float4*)(src + (size_t)c * N_DIM);
  ushort4* orow = (ushort4*)(dst + (size_t)c * N_DIM);
  int tid = threadIdx.x;
  float s = 0.f;
  for (int i = tid; i < N_DIM / 4; i += 256) {
    float4 v = row[i];
    s += v.x + v.y + v.z + v.w;
    ushort4 o;
    o.x = f2b(v.x); o.y = f2b(v.y); o.z = f2b(v.z); o.w = f2b(v.w);
    orow[i] = o;
  }
#pragma unroll
  for (int off = 1; off < 64; off <<= 1) s += __shfl_xor(s, off);
  __shared__ float red[4];
  if ((tid & 63) == 0) red[tid >> 6] = s;
  __syncthreads();
  if (tid == 0) mout[c] = (red[0] + red[1] + red[2] + red[3]) * (1.f / (float)N_DIM);
}

// ---------------- k2: weight conversion + projected means ----------------
__global__ void k2_wconv(const float* __restrict__ Wv, const float* __restrict__ Wq,
                         const float* __restrict__ Wk,
                         const float* __restrict__ xmean, const float* __restrict__ ymean,
                         unsigned short* __restrict__ Wvb, unsigned short* __restrict__ Wqb,
                         unsigned short* __restrict__ Wkb,
                         float* __restrict__ qmean, float* __restrict__ kmean) {
  int b = blockIdx.x, t = threadIdx.x;
  if (b < 256) {
    int i = b * 256 + t; Wvb[i] = f2b(Wv[i]);
  } else if (b < 320) {
    int i = (b - 256) * 256 + t; Wqb[i] = f2b(Wq[i]);
  } else if (b < 384) {
    int i = (b - 320) * 256 + t; Wkb[i] = f2b(Wk[i]);
  } else if (t < 128) {
    // qmean[p] = Wq[p,:] . xmean   (bias cancels in centering)
    int p = t & 63;
    const float* W = (t < 64) ? Wq : Wk;
    const float* mv = (t < 64) ? xmean : ymean;
    float s = 0.f;
    for (int cc = 0; cc < 256; cc++) s += W[p * 256 + cc] * mv[cc];
    ((t < 64) ? qmean : kmean)[p] = s;
  }
}

// ---------------- k3: MFMA projections ----------------
// blocks 0..143: V-tile (V[c][m]); 144..287: Q-tile (Q[n][p]); 288..431: K-tile
__global__ void k3_proj(const unsigned short* __restrict__ xb, const unsigned short* __restrict__ yb,
                        const unsigned short* __restrict__ Wvb, const unsigned short* __restrict__ Wqb,
                        const unsigned short* __restrict__ Wkb,
                        const float* __restrict__ qmean, const float* __restrict__ kmean,
                        unsigned short* __restrict__ Qb, unsigned short* __restrict__ Kb,
                        unsigned short* __restrict__ Vb) {
  __shared__ unsigned short T[64][264];  // transposed input tile [m/n][c]
  int b = blockIdx.x;
  int role = b / NT;       // 0=V 1=Q 2=K
  int tile = b % NT;
  int m0 = tile * 64;
  int tid = threadIdx.x;
  int w = tid >> 6, lane = tid & 63, l16 = lane & 15, g4 = lane >> 4;

  const unsigned short* src = (role == 1) ? xb : yb;
  {
    int c = tid;  // 256 threads = 256 channels
    const unsigned short* sr = src + (size_t)c * N_DIM + m0;
#pragma unroll
    for (int j = 0; j < 8; j++) {
      ushort8 v = *(const ushort8*)&sr[j * 8];
#pragma unroll
      for (int i = 0; i < 8; i++) T[j * 8 + i][c] = v[i];
    }
  }
  __syncthreads();

  if (role == 0) {
    // rows = c_out (wave owns 64), cols = m (64), k = c_in (256)
    f32x4 acc[4][4];
#pragma unroll
    for (int rf = 0; rf < 4; rf++)
#pragma unroll
      for (int cf = 0; cf < 4; cf++) acc[rf][cf] = (f32x4)0.f;
#pragma unroll
    for (int kk = 0; kk < 8; kk++) {
      short8 bf[4];
#pragma unroll
      for (int cf = 0; cf < 4; cf++)
        bf[cf] = *(const short8*)&T[cf * 16 + l16][kk * 32 + g4 * 8];
#pragma unroll
      for (int rf = 0; rf < 4; rf++) {
        short8 af = *(const short8*)&Wvb[(size_t)(w * 64 + rf * 16 + l16) * 256 + kk * 32 + g4 * 8];
#pragma unroll
        for (int cf = 0; cf < 4; cf++) acc[rf][cf] = mfma16(af, bf[cf], acc[rf][cf]);
      }
    }
#pragma unroll
    for (int rf = 0; rf < 4; rf++)
#pragma unroll
      for (int cf = 0; cf < 4; cf++)
#pragma unroll
        for (int r = 0; r < 4; r++) {
          int co = w * 64 + rf * 16 + g4 * 4 + r;
          int m = m0 + cf * 16 + l16;
          Vb[(size_t)co * N_DIM + m] = f2b(acc[rf][cf][r]);
        }
  } else {
    const unsigned short* Wb = (role == 1) ? Wqb : Wkb;
    const float* mean = (role == 1) ? qmean : kmean;
    unsigned short* Ob = (role == 1) ? Qb : Kb;
    // rows = n (wave owns 16), cols = p (64), k = c (256)
    f32x4 acc[4];
#pragma unroll
    for (int cf = 0; cf < 4; cf++) acc[cf] = (f32x4)0.f;
#pragma unroll
    for (int kk = 0; kk < 8; kk++) {
      short8 af = *(const short8*)&T[w * 16 + l16][kk * 32 + g4 * 8];
#pragma unroll
      for (int cf = 0; cf < 4; cf++) {
        short8 bf = *(const short8*)&Wb[(size_t)(cf * 16 + l16) * 256 + kk * 32 + g4 * 8];
        acc[cf] = mfma16(af, bf, acc[cf]);
      }
    }
#pragma unroll
    for (int cf = 0; cf < 4; cf++)
#pragma unroll
      for (int r = 0; r < 4; r++) {
        int n = m0 + w * 16 + g4 * 4 + r;
        int p = cf * 16 + l16;
        Ob[(size_t)n * 64 + p] = f2b(acc[cf][r] - mean[p]);
      }
  }
}

// ---------------- k4: flash attention (wave-owns-rows) ----------------
// grid 576: b&3 = M-split, b>>2 = n-tile. 4 waves; wave w owns Q-rows
// [n0+w*16, n0+w*16+16) across the FULL m extent -> wave-local softmax.
__global__ __launch_bounds__(256, 2)
void k4_attn(const unsigned short* __restrict__ Qb, const unsigned short* __restrict__ Kb,
             const unsigned short* __restrict__ Vb,
             unsigned short* __restrict__ po, float* __restrict__ m_arr, float* __restrict__ l_arr) {
  __shared__ unsigned short Kt[64][72];
  __shared__ unsigned short Vt[256][72];
  __shared__ unsigned short Pt[64][72];   // wave-private 16-row strips

  int b = blockIdx.x;
  int s = b & (SPLITS - 1);
  int n0 = (b >> 2) * 64;
  int tid = threadIdx.x;
  int w = tid >> 6, lane = tid & 63, l16 = lane & 15, g4 = lane >> 4;

  // Q A-fragments straight from global: row = l16 -> n = n0 + w*16 + l16
  short8 qf[2];
  {
    const unsigned short* qrow = Qb + (size_t)(n0 + w * 16 + l16) * 64;
    qf[0] = *(const short8*)&qrow[g4 * 8];
    qf[1] = *(const short8*)&qrow[32 + g4 * 8];
  }

  f32x4 acc[16];                 // O strip: rows n (g4*4+r), cols c = cfc*16+l16
#pragma unroll
  for (int i = 0; i < 16; i++) acc[i] = (f32x4)0.f;
  float mreg[4], lreg[4];        // per-lane copies for rows n = g4*4 + r
#pragma unroll
  for (int r = 0; r < 4; r++) { mreg[r] = -3e38f; lreg[r] = 0.f; }

  for (int t = 0; t < KV_TILES; t++) {
    int m0 = s * MQ + t * 64;
    // stage K (8KB) + V (32KB)
    for (int idx = tid; idx < 64 * 8; idx += 256) {
      int r = idx >> 3, j = idx & 7;
      *(ushort8*)&Kt[r][j * 8] = *(const ushort8*)&Kb[(size_t)(m0 + r) * 64 + j * 8];
    }
    for (int idx = tid; idx < 256 * 8; idx += 256) {
      int r = idx >> 3, j = idx & 7;
      *(ushort8*)&Vt[r][j * 8] = *(const ushort8*)&Vb[(size_t)r * N_DIM + m0 + j * 8];
    }
    __syncthreads();

    // QK^T: S[16n x 64m] per wave. D: row=n(g4*4+r), col=m(cf*16+l16)
    f32x4 sa[4];
#pragma unroll
    for (int cf = 0; cf < 4; cf++) sa[cf] = (f32x4)0.f;
#pragma unroll
    for (int kk = 0; kk < 2; kk++) {
#pragma unroll
      for (int cf = 0; cf < 4; cf++) {
        short8 kf = *(const short8*)&Kt[cf * 16 + l16][kk * 32 + g4 * 8];
        sa[cf] = mfma16(qf[kk], kf, sa[cf]);
      }
    }

    // wave-local online softmax (rows r; reduce over cf + 16-lane group)
    float f[4];
#pragma unroll
    for (int r = 0; r < 4; r++) {
      float v = fmaxf(fmaxf(sa[0][r], sa[1][r]), fmaxf(sa[2][r], sa[3][r]));
#pragma unroll
      for (int off = 1; off < 16; off <<= 1) v = fmaxf(v, __shfl_xor(v, off));
      float mnew = fmaxf(mreg[r], v);
      f[r] = __expf(mreg[r] - mnew);
      mreg[r] = mnew;
    }
    float p[4][4];
#pragma unroll
    for (int cf = 0; cf < 4; cf++)
#pragma unroll
      for (int r = 0; r < 4; r++) p[cf][r] = __expf(sa[cf][r] - mreg[r]);
#pragma unroll
    for (int r = 0; r < 4; r++) {
      float sv = p[0][r] + p[1][r] + p[2][r] + p[3][r];
#pragma unroll
      for (int off = 1; off < 16; off <<= 1) sv += __shfl_xor(sv, off);
      lreg[r] = lreg[r] * f[r] + sv;
    }
    // rescale O accumulator
#pragma unroll
    for (int cfc = 0; cfc < 16; cfc++)
#pragma unroll
      for (int r = 0; r < 4; r++) acc[cfc][r] *= f[r];

    // P -> LDS (wave-private rows; intra-wave RAW, no barrier)
#pragma unroll
    for (int cf = 0; cf < 4; cf++)
#pragma unroll
      for (int r = 0; r < 4; r++)
        Pt[w * 16 + g4 * 4 + r][cf * 16 + l16] = f2b(p[cf][r]);

    // PV: A = P strip (row=l16), B = V[c][m]
#pragma unroll
    for (int kk = 0; kk < 2; kk++) {
      short8 pf = *(const short8*)&Pt[w * 16 + l16][kk * 32 + g4 * 8];
#pragma unroll
      for (int cfc = 0; cfc < 16; cfc++) {
        short8 vf = *(const short8*)&Vt[cfc * 16 + l16][kk * 32 + g4 * 8];
        acc[cfc] = mfma16(pf, vf, acc[cfc]);
      }
    }
    __syncthreads();   // protect Kt/Vt before next stage
  }

  // epilogue: unnormalized bf16 partials + stats
  unsigned short* poS = po + (size_t)s * N_DIM * C_DIM;
#pragma unroll
  for (int cfc = 0; cfc < 16; cfc++)
#pragma unroll
    for (int r = 0; r < 4; r++) {
      int n = n0 + w * 16 + g4 * 4 + r;
      int c = cfc * 16 + l16;
      poS[(size_t)n * C_DIM + c] = f2b(acc[cfc][r]);
    }
  if (l16 == 0) {
#pragma unroll
    for (int r = 0; r < 4; r++) {
      int n = n0 + w * 16 + g4 * 4 + r;
      m_arr[s * N_DIM + n] = mreg[r];
      l_arr[s * N_DIM + n] = lreg[r];
    }
  }
}

// ---------------- k5: combine 4 splits, transpose to [C][N], gamma ----------------
__global__ void k5_combine(const unsigned short* __restrict__ po, const float* __restrict__ m_arr,
                           const float* __restrict__ l_arr, const float* __restrict__ gamma,
                           float* __restrict__ out) {
  __shared__ float TT[64][65];
  int b = blockIdx.x;
  int c0 = (b & 3) * 64;
  int n0 = (b >> 2) * 64;
  float g = gamma[0];
  int tid = threadIdx.x;
#pragma unroll
  for (int rr = 0; rr < 16; rr++) {
    int idx = rr * 256 + tid;
    int nl = idx >> 6, cl = idx & 63;
    int n = n0 + nl;
    float m0v = m_arr[n], m1v = m_arr[N_DIM + n];
    float m2v = m_arr[2 * N_DIM + n], m3v = m_arr[3 * N_DIM + n];
    float M = fmaxf(fmaxf(m0v, m1v), fmaxf(m2v, m3v));
    float w0 = __expf(m0v - M), w1 = __expf(m1v - M);
    float w2 = __expf(m2v - M), w3 = __expf(m3v - M);
    float denom = l_arr[n] * w0 + l_arr[N_DIM + n] * w1 +
                  l_arr[2 * N_DIM + n] * w2 + l_arr[3 * N_DIM + n] * w3;
    float v0 = b2f(po[(size_t)n * C_DIM + c0 + cl]);
    float v1 = b2f(po[((size_t)N_DIM + n) * C_DIM + c0 + cl]);
    float v2 = b2f(po[((size_t)2 * N_DIM + n) * C_DIM + c0 + cl]);
    float v3 = b2f(po[((size_t)3 * N_DIM + n) * C_DIM + c0 + cl]);
    TT[cl][nl] = (v0 * w0 + v1 * w1 + v2 * w2 + v3 * w3) / denom;
  }
  __syncthreads();
#pragma unroll
  for (int rr = 0; rr < 16; rr++) {
    int idx = rr * 256 + tid;
    int cl = idx >> 6, nl = idx & 63;
    out[(size_t)(c0 + cl) * N_DIM + n0 + nl] = g * TT[cl][nl];
  }
}

// ---------------- launch ----------------
extern "C" void kernel_launch(void* const* d_in, const int* in_sizes, int n_in,
                              void* d_out, int out_size, void* d_ws, size_t ws_size,
                              hipStream_t stream) {
  const float* x  = (const float*)d_in[0];
  const float* y  = (const float*)d_in[1];
  const float* Wv = (const float*)d_in[2];
  const float* Wq = (const float*)d_in[3];
  const float* Wk = (const float*)d_in[5];
  const float* gamma = (const float*)d_in[7];
  float* out = (float*)d_out;

  char* ws = (char*)d_ws;
  constexpr size_t OFF_XMEAN = 0;
  constexpr size_t OFF_YMEAN = 1024;
  constexpr size_t OFF_QMEAN = 2048;
  constexpr size_t OFF_KMEAN = 2560;
  constexpr size_t OFF_XB    = 4096;
  constexpr size_t OFF_YB    = OFF_XB + 4718592;
  constexpr size_t OFF_WVB   = OFF_YB + 4718592;
  constexpr size_t OFF_WQB   = OFF_WVB + 131072;
  constexpr size_t OFF_WKB   = OFF_WQB + 32768;
  constexpr size_t OFF_QB    = OFF_WKB + 32768;
  constexpr size_t OFF_KB    = OFF_QB + 1179648;
  constexpr size_t OFF_VB    = OFF_KB + 1179648;
  constexpr size_t OFF_PO    = OFF_VB + 4718592;                 // 4 splits bf16
  constexpr size_t OFF_M     = OFF_PO + (size_t)SPLITS * N_DIM * C_DIM * 2;
  constexpr size_t OFF_L     = OFF_M + (size_t)SPLITS * N_DIM * 4;  // total ~36 MB

  float* xmean = (float*)(ws + OFF_XMEAN);
  float* ymean = (float*)(ws + OFF_YMEAN);
  float* qmean = (float*)(ws + OFF_QMEAN);
  float* kmean = (float*)(ws + OFF_KMEAN);
  unsigned short* xb  = (unsigned short*)(ws + OFF_XB);
  unsigned short* yb  = (unsigned short*)(ws + OFF_YB);
  unsigned short* Wvb = (unsigned short*)(ws + OFF_WVB);
  unsigned short* Wqb = (unsigned short*)(ws + OFF_WQB);
  unsigned short* Wkb = (unsigned short*)(ws + OFF_WKB);
  unsigned short* Qb  = (unsigned short*)(ws + OFF_QB);
  unsigned short* Kb  = (unsigned short*)(ws + OFF_KB);
  unsigned short* Vb  = (unsigned short*)(ws + OFF_VB);
  unsigned short* po  = (unsigned short*)(ws + OFF_PO);
  float* m_arr = (float*)(ws + OFF_M);
  float* l_arr = (float*)(ws + OFF_L);

  k1_mean_conv<<<512, 256, 0, stream>>>(x, y, xb, yb, xmean, ymean);
  k2_wconv<<<385, 256, 0, stream>>>(Wv, Wq, Wk, xmean, ymean, Wvb, Wqb, Wkb, qmean, kmean);
  k3_proj<<<432, 256, 0, stream>>>(xb, yb, Wvb, Wqb, Wkb, qmean, kmean, Qb, Kb, Vb);
  k4_attn<<<NT * SPLITS, 256, 0, stream>>>(Qb, Kb, Vb, po, m_arr, l_arr);
  k5_combine<<<576, 256, 0, stream>>>(po, m_arr, l_arr, gamma, out);
}